// Round 12
// baseline (150.025 us; speedup 1.0000x reference)
//
#include <hip/hip_runtime.h>
#include <hip/hip_bf16.h>
#include <math.h>

// Problem constants
#define DIM   512
#define NTR   16384
#define NT    8192
#define NCLS  16
#define NROWS (NTR + NT)   // 24576 projection rows

// simmain tiling (r7 skeleton): wave owns one 16-i tile; block = 4 waves =
// 64 i's, one 1024-j chunk. Grid (NT/64, JS) = (128, 16) = 2048 blocks.
// JS=16 keeps the atomic flush at 33 MB (r8/r11: 66 MB costs ~+20 us).
#define JS     16                  // j-splits
#define JC     (NTR / JS)          // 1024 j per chunk
#define STEPS  (JC / 32)           // 32 K-steps (32 j each) per wave
#define NSTEPS (NTR / 32)          // 512 global K-steps

#define PROJ_BLOCKS (NROWS / 16)          // 1536 (16 rows/block, 4/wave)
#define PREP_BLOCKS ((NSTEPS * 64) / 256) // 128 (y-bake + accumulator zeroing)

// ws layout (floats): kq [24576][2] | numer [8192][16] | denom [8192] |
//                     yfh (bf16 A-frag plane, single hi plane)
#define WS_KQ_F    (NROWS * 2)           // 49152
#define WS_NUMER_F (NT * NCLS)           // 131072
#define WS_DENOM_F (NT)                  // 8192
#define WS_ZERO_V4 ((WS_NUMER_F + WS_DENOM_F) / 4)   // 34816 float4s

typedef __attribute__((ext_vector_type(8))) short short8;
typedef __attribute__((ext_vector_type(4))) float f32x4;
typedef __attribute__((ext_vector_type(4))) unsigned int uint4v;

static __device__ __forceinline__ short f2bf(float f) {   // RNE (prep only)
    unsigned u = __float_as_uint(f);
    return (short)((u + 0x7FFFu + ((u >> 16) & 1u)) >> 16);
}
// Pack 2 positive floats to bf16x2 (round-half-up): 2 adds + 1 v_perm.
static __device__ __forceinline__ unsigned pkbf(float a, float b) {
    unsigned ua = __float_as_uint(a) + 0x8000u;
    unsigned ub = __float_as_uint(b) + 0x8000u;
    return __builtin_amdgcn_perm(ub, ua, 0x07060302);   // (bf(b)<<16)|bf(a)
}

// ---------------------------------------------------------------------------
// Kernel 1 (fused prep): blocks [0,1536) = projection (4 rows/wave, 8
// independent loads + 8 parallel shuffle-reduce chains); blocks [1536,1664) =
// ytr^T bf16 bake in MFMA A-frag order (single hi plane; round-12 drops the
// lo residual — error budget: y-bf16 half-ULP ~2-4e-3 on top of e-rounding
// 1.95e-3, vs threshold 1.07e-2) + zeroing of numer/denom.
// NO cross-block fences anywhere (round 6: device-scope fences cost ~full-
// L2-writeback per block on multi-XCD CDNA4).
// ---------------------------------------------------------------------------
__global__ __launch_bounds__(256) void prep_kernel(
    const float* __restrict__ xtr, const float* __restrict__ xt,
    const float* __restrict__ A, const float* __restrict__ ytr,
    float* __restrict__ kq, short* __restrict__ yfh,
    float* __restrict__ zbase)
{
    const int b = blockIdx.x;
    if (b < PROJ_BLOCKS) {
        const int wave = threadIdx.x >> 6;
        const int lane = threadIdx.x & 63;
        const int row0 = b * 16 + wave * 4;

        const float* xp[4];
#pragma unroll
        for (int r = 0; r < 4; ++r) {
            const int row = row0 + r;
            xp[r] = (row < NTR) ? (xtr + (size_t)row * DIM)
                                : (xt + (size_t)(row - NTR) * DIM);
        }
        float a0[4] = {0.f, 0.f, 0.f, 0.f}, a1[4] = {0.f, 0.f, 0.f, 0.f};
#pragma unroll
        for (int t = 0; t < 2; ++t) {
            const int d = lane * 4 + t * 256;
            float4 A0 = *(const float4*)(A + 2 * d);       // A[d..d+1][0..1]
            float4 A1 = *(const float4*)(A + 2 * d + 4);   // A[d+2..d+3][0..1]
#pragma unroll
            for (int r = 0; r < 4; ++r) {
                float4 u = *(const float4*)(xp[r] + d);
                a0[r] += u.x * A0.x + u.y * A0.z + u.z * A1.x + u.w * A1.z;
                a1[r] += u.x * A0.y + u.y * A0.w + u.z * A1.y + u.w * A1.w;
            }
        }
#pragma unroll
        for (int off = 32; off >= 1; off >>= 1) {
#pragma unroll
            for (int r = 0; r < 4; ++r) {
                a0[r] += __shfl_xor(a0[r], off, 64);
                a1[r] += __shfl_xor(a1[r], off, 64);
            }
        }
        if (lane == 0) {
            *(float4*)(kq + row0 * 2)     = make_float4(a0[0], a1[0], a0[1], a1[1]);
            *(float4*)(kq + row0 * 2 + 4) = make_float4(a0[2], a1[2], a0[3], a1[3]);
        }
    } else {
        const int idx = (b - PROJ_BLOCKS) * 256 + threadIdx.x;  // 0..32767
        // zero numer+denom (34816 float4s over 32768 threads)
        float4 z = make_float4(0.f, 0.f, 0.f, 0.f);
        for (int p = idx; p < WS_ZERO_V4; p += PREP_BLOCKS * 256)
            ((float4*)zbase)[p] = z;

        const int l   = idx & 63;
        const int s   = idx >> 6;
        const int cls = l & 15;
        const int jb  = s * 32 + (l >> 4) * 8;
        short8 hi;
#pragma unroll
        for (int t = 0; t < 8; ++t)
            hi[t] = f2bf(ytr[(size_t)(jb + t) * NCLS + cls]);
        ((short8*)yfh)[idx] = hi;
    }
}

// ---------------------------------------------------------------------------
// Kernel 2: main. Grid (NT/64, JS) = (128, 16) = 2048 blocks (8 blocks/CU).
// Round-12 structure: ZERO LDS — the quad-uniform k-octets are loaded
// straight from global kq (L1/L2-hot, 4 coalesced 16B segments per wave-
// step), removing ~48 cyc/step of LDS data-return demand (r11 accounting:
// LDS ~50% busy was a co-bottleneck), the staging loop, and the barrier.
// Single y plane (hi only) -> one y-load stream + 2 MFMAs per step
// (Y@E -> numer, Ones@E -> denom; same bf16 e in both so peaked-softmax
// rows cancel exactly in the ratio).
// Fire-and-forget atomic flush; separate finalize kernel (round 6: fences =
// ~full-L2-writeback per block).
// ---------------------------------------------------------------------------
__global__ __launch_bounds__(256) void simmain_kernel(
    const float* __restrict__ kq, const short* __restrict__ yfh,
    float* __restrict__ numer, float* __restrict__ denom)
{
    const int tid  = threadIdx.x;
    const int wave = tid >> 6;
    const int lane = tid & 63;
    const int j0   = blockIdx.y * JC;

    const int i0   = (blockIdx.x * 4 + wave) * 16;
    const int m    = lane & 15;
    const int quad = lane >> 4;

    // q for this lane's test point, pre-scaled by log2(e) so e = exp2(logit')
    const float2 qv = *(const float2*)(kq + 2 * (NTR + i0 + m));
    const float q0 = qv.x * 1.4426950408889634f;
    const float q1 = qv.y * 1.4426950408889634f;

    f32x4 acc  = {0.f, 0.f, 0.f, 0.f};
    f32x4 acc2 = {0.f, 0.f, 0.f, 0.f};
    short8 ones;
#pragma unroll
    for (int t = 0; t < 8; ++t) ones[t] = (short)0x3F80;   // bf16 1.0

    const short8* __restrict__ yhp = ((const short8*)yfh) + (size_t)blockIdx.y * (STEPS * 64) + lane;
    // quad's first k-octet (float4 view of kq + 2*j0): step s octet lives at
    // float4 index s*16 + quad*4
    const float4* __restrict__ kx = ((const float4*)(kq + 2 * j0)) + quad * 4;

#pragma unroll 4
    for (int s = 0; s < STEPS; ++s) {
        const short8 yh = yhp[s * 64];          // coalesced dwordx4, L2-hot
        const float4* kp = kx + s * 16;         // quad-uniform global b128
        const float4 ka = kp[0], kb = kp[1], kc = kp[2], kd = kp[3];

        const float e0 = __builtin_amdgcn_exp2f(fmaf(q1, ka.y, q0 * ka.x));
        const float e1 = __builtin_amdgcn_exp2f(fmaf(q1, ka.w, q0 * ka.z));
        const float e2 = __builtin_amdgcn_exp2f(fmaf(q1, kb.y, q0 * kb.x));
        const float e3 = __builtin_amdgcn_exp2f(fmaf(q1, kb.w, q0 * kb.z));
        const float e4 = __builtin_amdgcn_exp2f(fmaf(q1, kc.y, q0 * kc.x));
        const float e5 = __builtin_amdgcn_exp2f(fmaf(q1, kc.w, q0 * kc.z));
        const float e6 = __builtin_amdgcn_exp2f(fmaf(q1, kd.y, q0 * kd.x));
        const float e7 = __builtin_amdgcn_exp2f(fmaf(q1, kd.w, q0 * kd.z));

        uint4v ep;
        ep[0] = pkbf(e0, e1); ep[1] = pkbf(e2, e3);
        ep[2] = pkbf(e4, e5); ep[3] = pkbf(e6, e7);
        const short8 eb = __builtin_bit_cast(short8, ep);

        acc  = __builtin_amdgcn_mfma_f32_16x16x32_bf16(yh,   eb, acc,  0, 0, 0);
        acc2 = __builtin_amdgcn_mfma_f32_16x16x32_bf16(ones, eb, acc2, 0, 0, 0);
    }

    // Flush: lane holds numer[i0+m][quad*4+r] = acc[r]; dsum(i0+m) = acc2[*]
    float* nrow = numer + (size_t)(i0 + m) * NCLS + quad * 4;
#pragma unroll
    for (int r = 0; r < 4; ++r)
        atomicAdd(nrow + r, acc[r]);
    if (quad == 0)
        atomicAdd(denom + i0 + m, acc2[0]);
}

// ---------------------------------------------------------------------------
// Kernel 3: finalize — divide numerators by softmax denominator.
// ---------------------------------------------------------------------------
__global__ __launch_bounds__(256) void finalize_kernel(
    const float* __restrict__ numer, const float* __restrict__ denom,
    float* __restrict__ out)
{
    const int idx = blockIdx.x * 256 + threadIdx.x;   // < NT*NCLS
    out[idx] = numer[idx] / denom[idx >> 4];
}

// ---------------------------------------------------------------------------
extern "C" void kernel_launch(void* const* d_in, const int* in_sizes, int n_in,
                              void* d_out, int out_size, void* d_ws, size_t ws_size,
                              hipStream_t stream)
{
    const float* xtr = (const float*)d_in[0];   // [16384][512]
    const float* ytr = (const float*)d_in[1];   // [16384][16]
    const float* xt  = (const float*)d_in[2];   // [8192][512]
    const float* A   = (const float*)d_in[3];   // [512][2]
    float* out = (float*)d_out;                 // [8192][16]

    float* kq    = (float*)d_ws;                       // 49152 floats
    float* numer = kq + WS_KQ_F;                       // 131072 floats
    float* denom = numer + WS_NUMER_F;                 // 8192 floats
    short* yfh   = (short*)(denom + WS_DENOM_F);       // 262144 shorts (512 KB)

    prep_kernel<<<PROJ_BLOCKS + PREP_BLOCKS, 256, 0, stream>>>(
        xtr, xt, A, ytr, kq, yfh, numer);
    simmain_kernel<<<dim3(NT / 64, JS), 256, 0, stream>>>(
        kq, yfh, numer, denom);
    finalize_kernel<<<(NT * NCLS) / 256, 256, 0, stream>>>(numer, denom, out);
}

// Round 13
// 124.806 us; speedup vs baseline: 1.2021x; 1.2021x over previous
//
#include <hip/hip_runtime.h>
#include <hip/hip_bf16.h>
#include <math.h>

// Problem constants
#define DIM   512
#define NTR   16384
#define NT    8192
#define NCLS  16
#define NROWS (NTR + NT)   // 24576 projection rows

// simmain tiling (r7 skeleton): wave owns one 16-i tile; block = 4 waves =
// 64 i's, one 1024-j chunk. Grid (NT/64, JS) = (128, 16) = 2048 blocks.
// JS=16 keeps the atomic flush at 33 MB (r8/r11: 66 MB costs ~+20 us).
#define JS     16                  // j-splits
#define JC     (NTR / JS)          // 1024 j per chunk
#define STEPS  (JC / 32)           // 32 K-steps (32 j each) per wave
#define NSTEPS (NTR / 32)          // 512 global K-steps

#define PROJ_BLOCKS (NROWS / 16)          // 1536 (16 rows/block, 4/wave)
#define PREP_BLOCKS ((NSTEPS * 64) / 256) // 128 (y-bake + accumulator zeroing)

// ws layout (floats): kq [24576][2] | numer [8192][16] | denom [8192] |
//                     yfh (bf16 A-frag plane, single hi plane — r12 measured
//                     identical absmax without the lo residual)
#define WS_KQ_F    (NROWS * 2)           // 49152
#define WS_NUMER_F (NT * NCLS)           // 131072
#define WS_DENOM_F (NT)                  // 8192
#define WS_ZERO_V4 ((WS_NUMER_F + WS_DENOM_F) / 4)   // 34816 float4s

typedef __attribute__((ext_vector_type(8))) short short8;
typedef __attribute__((ext_vector_type(4))) float f32x4;
typedef __attribute__((ext_vector_type(4))) unsigned int uint4v;

static __device__ __forceinline__ short f2bf(float f) {   // RNE (prep only)
    unsigned u = __float_as_uint(f);
    return (short)((u + 0x7FFFu + ((u >> 16) & 1u)) >> 16);
}
// Pack 2 positive floats to bf16x2 (round-half-up): 2 adds + 1 v_perm.
static __device__ __forceinline__ unsigned pkbf(float a, float b) {
    unsigned ua = __float_as_uint(a) + 0x8000u;
    unsigned ub = __float_as_uint(b) + 0x8000u;
    return __builtin_amdgcn_perm(ub, ua, 0x07060302);   // (bf(b)<<16)|bf(a)
}

// ---------------------------------------------------------------------------
// Kernel 1 (fused prep): blocks [0,1536) = projection (4 rows/wave, 8
// independent loads + 8 parallel shuffle-reduce chains); blocks [1536,1664) =
// ytr^T bf16 bake in MFMA A-frag order (single plane) + zeroing of
// numer/denom. NO cross-block fences (round 6: device-scope fences cost
// ~full-L2-writeback per block on multi-XCD CDNA4).
// ---------------------------------------------------------------------------
__global__ __launch_bounds__(256) void prep_kernel(
    const float* __restrict__ xtr, const float* __restrict__ xt,
    const float* __restrict__ A, const float* __restrict__ ytr,
    float* __restrict__ kq, short* __restrict__ yfh,
    float* __restrict__ zbase)
{
    const int b = blockIdx.x;
    if (b < PROJ_BLOCKS) {
        const int wave = threadIdx.x >> 6;
        const int lane = threadIdx.x & 63;
        const int row0 = b * 16 + wave * 4;

        const float* xp[4];
#pragma unroll
        for (int r = 0; r < 4; ++r) {
            const int row = row0 + r;
            xp[r] = (row < NTR) ? (xtr + (size_t)row * DIM)
                                : (xt + (size_t)(row - NTR) * DIM);
        }
        float a0[4] = {0.f, 0.f, 0.f, 0.f}, a1[4] = {0.f, 0.f, 0.f, 0.f};
#pragma unroll
        for (int t = 0; t < 2; ++t) {
            const int d = lane * 4 + t * 256;
            float4 A0 = *(const float4*)(A + 2 * d);       // A[d..d+1][0..1]
            float4 A1 = *(const float4*)(A + 2 * d + 4);   // A[d+2..d+3][0..1]
#pragma unroll
            for (int r = 0; r < 4; ++r) {
                float4 u = *(const float4*)(xp[r] + d);
                a0[r] += u.x * A0.x + u.y * A0.z + u.z * A1.x + u.w * A1.z;
                a1[r] += u.x * A0.y + u.y * A0.w + u.z * A1.y + u.w * A1.w;
            }
        }
#pragma unroll
        for (int off = 32; off >= 1; off >>= 1) {
#pragma unroll
            for (int r = 0; r < 4; ++r) {
                a0[r] += __shfl_xor(a0[r], off, 64);
                a1[r] += __shfl_xor(a1[r], off, 64);
            }
        }
        if (lane == 0) {
            *(float4*)(kq + row0 * 2)     = make_float4(a0[0], a1[0], a0[1], a1[1]);
            *(float4*)(kq + row0 * 2 + 4) = make_float4(a0[2], a1[2], a0[3], a1[3]);
        }
    } else {
        const int idx = (b - PROJ_BLOCKS) * 256 + threadIdx.x;  // 0..32767
        // zero numer+denom (34816 float4s over 32768 threads)
        float4 z = make_float4(0.f, 0.f, 0.f, 0.f);
        for (int p = idx; p < WS_ZERO_V4; p += PREP_BLOCKS * 256)
            ((float4*)zbase)[p] = z;

        const int l   = idx & 63;
        const int s   = idx >> 6;
        const int cls = l & 15;
        const int jb  = s * 32 + (l >> 4) * 8;
        short8 hi;
#pragma unroll
        for (int t = 0; t < 8; ++t)
            hi[t] = f2bf(ytr[(size_t)(jb + t) * NCLS + cls]);
        ((short8*)yfh)[idx] = hi;
    }
}

// ---------------------------------------------------------------------------
// Kernel 2: main. Grid (NT/64, JS) = (128, 16) = 2048 blocks. ALL-LDS K-loop:
// the block stages BOTH its k-chunk (8 KB fp32) and its y-chunk (32 KB bf16
// A-frags, single plane) into LDS once, then the 32-step loop touches only
// LDS + VALU — no global loads at all. Rationale (r7 vs r12 accounting):
// r7's 400-wall/190-issue gap was exposed L2 latency on the per-wave y
// stream (4 waves redundantly re-loading the same frags); LDS serves them
// block-shared at ~120 cyc. 40 KB LDS -> 4 blocks/CU = 16 waves/CU (what r7
// actually achieved). Per step: 1 lane-contiguous ds_read_b128 (y) + 4
// quad-broadcast b128 (k, 2-way bank alias = free), 8 raw v_exp_f32, v_perm
// pack, 2 MFMAs (Y@E -> numer, Ones@E -> denom; same bf16 e in both).
// Fire-and-forget atomic flush; separate finalize kernel (round 6).
// ---------------------------------------------------------------------------
__global__ __launch_bounds__(256) void simmain_kernel(
    const float* __restrict__ kq, const short* __restrict__ yfh,
    float* __restrict__ numer, float* __restrict__ denom)
{
    __shared__ float  ks[JC * 2];        // 8 KB fp32 k-chunk
    __shared__ short8 ys[STEPS * 64];    // 32 KB bf16 y-frags (A-op order)

    const int tid  = threadIdx.x;
    const int wave = tid >> 6;
    const int lane = tid & 63;
    const int j0   = blockIdx.y * JC;

    const int i0   = (blockIdx.x * 4 + wave) * 16;
    const int m    = lane & 15;
    const int quad = lane >> 4;

    // q load first (overlaps staging latency)
    const float2 qv = *(const float2*)(kq + 2 * (NTR + i0 + m));
    const float q0 = qv.x * 1.4426950408889634f;   // pre-scale by log2(e)
    const float q1 = qv.y * 1.4426950408889634f;

    {   // stage k (512 float4) + y (2048 float4-equivalents), coalesced
        const float4* ksrc = (const float4*)(kq + 2 * j0);
        float4* kdst = (float4*)ks;
        kdst[tid]       = ksrc[tid];
        kdst[tid + 256] = ksrc[tid + 256];
        const float4* ysrc = (const float4*)(yfh + (size_t)blockIdx.y * (STEPS * 64) * 8);
        float4* ydst = (float4*)ys;
#pragma unroll
        for (int p = 0; p < 8; ++p)
            ydst[tid + 256 * p] = ysrc[tid + 256 * p];
    }
    __syncthreads();

    f32x4 acc  = {0.f, 0.f, 0.f, 0.f};
    f32x4 acc2 = {0.f, 0.f, 0.f, 0.f};
    short8 ones;
#pragma unroll
    for (int t = 0; t < 8; ++t) ones[t] = (short)0x3F80;   // bf16 1.0

    const short8* __restrict__ yls = ys + lane;                 // + s*64 per step
    const float4* __restrict__ kx  = ((const float4*)ks) + quad * 4;

#pragma unroll 4
    for (int s = 0; s < STEPS; ++s) {
        const short8 yh = yls[s * 64];          // lane-contiguous ds_read_b128
        const float4* kp = kx + s * 16;         // quad-broadcast b128 reads
        const float4 ka = kp[0], kb = kp[1], kc = kp[2], kd = kp[3];

        const float e0 = __builtin_amdgcn_exp2f(fmaf(q1, ka.y, q0 * ka.x));
        const float e1 = __builtin_amdgcn_exp2f(fmaf(q1, ka.w, q0 * ka.z));
        const float e2 = __builtin_amdgcn_exp2f(fmaf(q1, kb.y, q0 * kb.x));
        const float e3 = __builtin_amdgcn_exp2f(fmaf(q1, kb.w, q0 * kb.z));
        const float e4 = __builtin_amdgcn_exp2f(fmaf(q1, kc.y, q0 * kc.x));
        const float e5 = __builtin_amdgcn_exp2f(fmaf(q1, kc.w, q0 * kc.z));
        const float e6 = __builtin_amdgcn_exp2f(fmaf(q1, kd.y, q0 * kd.x));
        const float e7 = __builtin_amdgcn_exp2f(fmaf(q1, kd.w, q0 * kd.z));

        uint4v ep;
        ep[0] = pkbf(e0, e1); ep[1] = pkbf(e2, e3);
        ep[2] = pkbf(e4, e5); ep[3] = pkbf(e6, e7);
        const short8 eb = __builtin_bit_cast(short8, ep);

        acc  = __builtin_amdgcn_mfma_f32_16x16x32_bf16(yh,   eb, acc,  0, 0, 0);
        acc2 = __builtin_amdgcn_mfma_f32_16x16x32_bf16(ones, eb, acc2, 0, 0, 0);
    }

    // Flush: lane holds numer[i0+m][quad*4+r] = acc[r]; dsum(i0+m) = acc2[*]
    float* nrow = numer + (size_t)(i0 + m) * NCLS + quad * 4;
#pragma unroll
    for (int r = 0; r < 4; ++r)
        atomicAdd(nrow + r, acc[r]);
    if (quad == 0)
        atomicAdd(denom + i0 + m, acc2[0]);
}

// ---------------------------------------------------------------------------
// Kernel 3: finalize — divide numerators by softmax denominator.
// ---------------------------------------------------------------------------
__global__ __launch_bounds__(256) void finalize_kernel(
    const float* __restrict__ numer, const float* __restrict__ denom,
    float* __restrict__ out)
{
    const int idx = blockIdx.x * 256 + threadIdx.x;   // < NT*NCLS
    out[idx] = numer[idx] / denom[idx >> 4];
}

// ---------------------------------------------------------------------------
extern "C" void kernel_launch(void* const* d_in, const int* in_sizes, int n_in,
                              void* d_out, int out_size, void* d_ws, size_t ws_size,
                              hipStream_t stream)
{
    const float* xtr = (const float*)d_in[0];   // [16384][512]
    const float* ytr = (const float*)d_in[1];   // [16384][16]
    const float* xt  = (const float*)d_in[2];   // [8192][512]
    const float* A   = (const float*)d_in[3];   // [512][2]
    float* out = (float*)d_out;                 // [8192][16]

    float* kq    = (float*)d_ws;                       // 49152 floats
    float* numer = kq + WS_KQ_F;                       // 131072 floats
    float* denom = numer + WS_NUMER_F;                 // 8192 floats
    short* yfh   = (short*)(denom + WS_DENOM_F);       // 262144 shorts (512 KB)

    prep_kernel<<<PROJ_BLOCKS + PREP_BLOCKS, 256, 0, stream>>>(
        xtr, xt, A, ytr, kq, yfh, numer);
    simmain_kernel<<<dim3(NT / 64, JS), 256, 0, stream>>>(
        kq, yfh, numer, denom);
    finalize_kernel<<<(NT * NCLS) / 256, 256, 0, stream>>>(numer, denom, out);
}

// Round 14
// 123.804 us; speedup vs baseline: 1.2118x; 1.0081x over previous
//
#include <hip/hip_runtime.h>
#include <hip/hip_bf16.h>
#include <math.h>

// Problem constants
#define DIM   512
#define NTR   16384
#define NT    8192
#define NCLS  16
#define NROWS (NTR + NT)   // 24576 projection rows

// simmain tiling: wave owns one 16-i tile; block = 8 waves (512 thr) = 128
// i's, one 1024-j chunk staged once in LDS (40 KB). Grid (NT/128, JS) =
// (64, 16) = 1024 blocks = 4 blocks/CU x 8 waves -> 32 waves/CU if the
// residency cap is concurrent-workgroups/CU (r7-r13: occupancy pinned at
// ~50% across all grids/LDS/VGPR configs -> testing the workgroup-cap
// hypothesis with bigger blocks).
#define JS     16                  // j-splits (33 MB atomic flush, r8/r11: 66 MB = +20 us)
#define JC     (NTR / JS)          // 1024 j per chunk
#define STEPS  (JC / 32)           // 32 K-steps (32 j each) per wave
#define NSTEPS (NTR / 32)          // 512 global K-steps

#define PROJ_BLOCKS (NROWS / 16)          // 1536 (16 rows/block, 4/wave)
#define PREP_BLOCKS ((NSTEPS * 64) / 256) // 128 (y-bake + accumulator zeroing)

// ws layout (floats): kq [24576][2] | numer [8192][16] | denom [8192] |
//                     yfh (bf16 A-frag plane, single plane — r12 measured
//                     identical absmax without the lo residual)
#define WS_KQ_F    (NROWS * 2)           // 49152
#define WS_NUMER_F (NT * NCLS)           // 131072
#define WS_DENOM_F (NT)                  // 8192
#define WS_ZERO_V4 ((WS_NUMER_F + WS_DENOM_F) / 4)   // 34816 float4s

typedef __attribute__((ext_vector_type(8))) short short8;
typedef __attribute__((ext_vector_type(4))) float f32x4;
typedef __attribute__((ext_vector_type(4))) unsigned int uint4v;

static __device__ __forceinline__ short f2bf(float f) {   // RNE (prep only)
    unsigned u = __float_as_uint(f);
    return (short)((u + 0x7FFFu + ((u >> 16) & 1u)) >> 16);
}
// Pack 2 positive floats to bf16x2 (round-half-up): 2 adds + 1 v_perm.
static __device__ __forceinline__ unsigned pkbf(float a, float b) {
    unsigned ua = __float_as_uint(a) + 0x8000u;
    unsigned ub = __float_as_uint(b) + 0x8000u;
    return __builtin_amdgcn_perm(ub, ua, 0x07060302);   // (bf(b)<<16)|bf(a)
}

// ---------------------------------------------------------------------------
// Kernel 1 (fused prep): blocks [0,1536) = projection (4 rows/wave, 8
// independent loads + 8 parallel shuffle-reduce chains); blocks [1536,1664) =
// ytr^T bf16 bake in MFMA A-frag order (single plane) + zeroing of
// numer/denom. NO cross-block fences (round 6: device-scope fences cost
// ~full-L2-writeback per block on multi-XCD CDNA4).
// ---------------------------------------------------------------------------
__global__ __launch_bounds__(256) void prep_kernel(
    const float* __restrict__ xtr, const float* __restrict__ xt,
    const float* __restrict__ A, const float* __restrict__ ytr,
    float* __restrict__ kq, short* __restrict__ yfh,
    float* __restrict__ zbase)
{
    const int b = blockIdx.x;
    if (b < PROJ_BLOCKS) {
        const int wave = threadIdx.x >> 6;
        const int lane = threadIdx.x & 63;
        const int row0 = b * 16 + wave * 4;

        const float* xp[4];
#pragma unroll
        for (int r = 0; r < 4; ++r) {
            const int row = row0 + r;
            xp[r] = (row < NTR) ? (xtr + (size_t)row * DIM)
                                : (xt + (size_t)(row - NTR) * DIM);
        }
        float a0[4] = {0.f, 0.f, 0.f, 0.f}, a1[4] = {0.f, 0.f, 0.f, 0.f};
#pragma unroll
        for (int t = 0; t < 2; ++t) {
            const int d = lane * 4 + t * 256;
            float4 A0 = *(const float4*)(A + 2 * d);       // A[d..d+1][0..1]
            float4 A1 = *(const float4*)(A + 2 * d + 4);   // A[d+2..d+3][0..1]
#pragma unroll
            for (int r = 0; r < 4; ++r) {
                float4 u = *(const float4*)(xp[r] + d);
                a0[r] += u.x * A0.x + u.y * A0.z + u.z * A1.x + u.w * A1.z;
                a1[r] += u.x * A0.y + u.y * A0.w + u.z * A1.y + u.w * A1.w;
            }
        }
#pragma unroll
        for (int off = 32; off >= 1; off >>= 1) {
#pragma unroll
            for (int r = 0; r < 4; ++r) {
                a0[r] += __shfl_xor(a0[r], off, 64);
                a1[r] += __shfl_xor(a1[r], off, 64);
            }
        }
        if (lane == 0) {
            *(float4*)(kq + row0 * 2)     = make_float4(a0[0], a1[0], a0[1], a1[1]);
            *(float4*)(kq + row0 * 2 + 4) = make_float4(a0[2], a1[2], a0[3], a1[3]);
        }
    } else {
        const int idx = (b - PROJ_BLOCKS) * 256 + threadIdx.x;  // 0..32767
        // zero numer+denom (34816 float4s over 32768 threads)
        float4 z = make_float4(0.f, 0.f, 0.f, 0.f);
        for (int p = idx; p < WS_ZERO_V4; p += PREP_BLOCKS * 256)
            ((float4*)zbase)[p] = z;

        const int l   = idx & 63;
        const int s   = idx >> 6;
        const int cls = l & 15;
        const int jb  = s * 32 + (l >> 4) * 8;
        short8 hi;
#pragma unroll
        for (int t = 0; t < 8; ++t)
            hi[t] = f2bf(ytr[(size_t)(jb + t) * NCLS + cls]);
        ((short8*)yfh)[idx] = hi;
    }
}

// ---------------------------------------------------------------------------
// Kernel 2: main. Grid (NT/128, JS) = (64, 16) = 1024 blocks of 512 threads
// (8 waves). ALL-LDS K-loop (r13): block stages its k-chunk (8 KB fp32) and
// y-chunk (32 KB bf16 A-frags) once; the 32-step loop touches only LDS +
// VALU. Each of the 8 waves owns one 16-i tile and shares the block's y/k
// copy (y-staging traffic also halves vs r13). Per step: 1 lane-contiguous
// ds_read_b128 (y) + 4 quad-broadcast b128 (k), 8 raw v_exp_f32, v_perm
// pack, 2 MFMAs (Y@E -> numer, Ones@E -> denom; same bf16 e in both).
// Fire-and-forget atomic flush; separate finalize kernel (round 6: fences =
// ~full-L2-writeback per block).
// ---------------------------------------------------------------------------
__global__ __launch_bounds__(512) void simmain_kernel(
    const float* __restrict__ kq, const short* __restrict__ yfh,
    float* __restrict__ numer, float* __restrict__ denom)
{
    __shared__ float  ks[JC * 2];        // 8 KB fp32 k-chunk
    __shared__ short8 ys[STEPS * 64];    // 32 KB bf16 y-frags (A-op order)

    const int tid  = threadIdx.x;        // 0..511
    const int wave = tid >> 6;           // 0..7
    const int lane = tid & 63;
    const int j0   = blockIdx.y * JC;

    const int i0   = (blockIdx.x * 8 + wave) * 16;
    const int m    = lane & 15;
    const int quad = lane >> 4;

    // q load first (overlaps staging latency)
    const float2 qv = *(const float2*)(kq + 2 * (NTR + i0 + m));
    const float q0 = qv.x * 1.4426950408889634f;   // pre-scale by log2(e)
    const float q1 = qv.y * 1.4426950408889634f;

    {   // stage k (512 float4, 1/thread) + y (2048 float4, 4/thread)
        const float4* ksrc = (const float4*)(kq + 2 * j0);
        ((float4*)ks)[tid] = ksrc[tid];
        const float4* ysrc = (const float4*)(yfh + (size_t)blockIdx.y * (STEPS * 64) * 8);
        float4* ydst = (float4*)ys;
#pragma unroll
        for (int p = 0; p < 4; ++p)
            ydst[tid + 512 * p] = ysrc[tid + 512 * p];
    }
    __syncthreads();

    f32x4 acc  = {0.f, 0.f, 0.f, 0.f};
    f32x4 acc2 = {0.f, 0.f, 0.f, 0.f};
    short8 ones;
#pragma unroll
    for (int t = 0; t < 8; ++t) ones[t] = (short)0x3F80;   // bf16 1.0

    const short8* __restrict__ yls = ys + lane;                 // + s*64 per step
    const float4* __restrict__ kx  = ((const float4*)ks) + quad * 4;

#pragma unroll 4
    for (int s = 0; s < STEPS; ++s) {
        const short8 yh = yls[s * 64];          // lane-contiguous ds_read_b128
        const float4* kp = kx + s * 16;         // quad-broadcast b128 reads
        const float4 ka = kp[0], kb = kp[1], kc = kp[2], kd = kp[3];

        const float e0 = __builtin_amdgcn_exp2f(fmaf(q1, ka.y, q0 * ka.x));
        const float e1 = __builtin_amdgcn_exp2f(fmaf(q1, ka.w, q0 * ka.z));
        const float e2 = __builtin_amdgcn_exp2f(fmaf(q1, kb.y, q0 * kb.x));
        const float e3 = __builtin_amdgcn_exp2f(fmaf(q1, kb.w, q0 * kb.z));
        const float e4 = __builtin_amdgcn_exp2f(fmaf(q1, kc.y, q0 * kc.x));
        const float e5 = __builtin_amdgcn_exp2f(fmaf(q1, kc.w, q0 * kc.z));
        const float e6 = __builtin_amdgcn_exp2f(fmaf(q1, kd.y, q0 * kd.x));
        const float e7 = __builtin_amdgcn_exp2f(fmaf(q1, kd.w, q0 * kd.z));

        uint4v ep;
        ep[0] = pkbf(e0, e1); ep[1] = pkbf(e2, e3);
        ep[2] = pkbf(e4, e5); ep[3] = pkbf(e6, e7);
        const short8 eb = __builtin_bit_cast(short8, ep);

        acc  = __builtin_amdgcn_mfma_f32_16x16x32_bf16(yh,   eb, acc,  0, 0, 0);
        acc2 = __builtin_amdgcn_mfma_f32_16x16x32_bf16(ones, eb, acc2, 0, 0, 0);
    }

    // Flush: lane holds numer[i0+m][quad*4+r] = acc[r]; dsum(i0+m) = acc2[*]
    float* nrow = numer + (size_t)(i0 + m) * NCLS + quad * 4;
#pragma unroll
    for (int r = 0; r < 4; ++r)
        atomicAdd(nrow + r, acc[r]);
    if (quad == 0)
        atomicAdd(denom + i0 + m, acc2[0]);
}

// ---------------------------------------------------------------------------
// Kernel 3: finalize — divide numerators by softmax denominator.
// ---------------------------------------------------------------------------
__global__ __launch_bounds__(256) void finalize_kernel(
    const float* __restrict__ numer, const float* __restrict__ denom,
    float* __restrict__ out)
{
    const int idx = blockIdx.x * 256 + threadIdx.x;   // < NT*NCLS
    out[idx] = numer[idx] / denom[idx >> 4];
}

// ---------------------------------------------------------------------------
extern "C" void kernel_launch(void* const* d_in, const int* in_sizes, int n_in,
                              void* d_out, int out_size, void* d_ws, size_t ws_size,
                              hipStream_t stream)
{
    const float* xtr = (const float*)d_in[0];   // [16384][512]
    const float* ytr = (const float*)d_in[1];   // [16384][16]
    const float* xt  = (const float*)d_in[2];   // [8192][512]
    const float* A   = (const float*)d_in[3];   // [512][2]
    float* out = (float*)d_out;                 // [8192][16]

    float* kq    = (float*)d_ws;                       // 49152 floats
    float* numer = kq + WS_KQ_F;                       // 131072 floats
    float* denom = numer + WS_NUMER_F;                 // 8192 floats
    short* yfh   = (short*)(denom + WS_DENOM_F);       // 262144 shorts (512 KB)

    prep_kernel<<<PROJ_BLOCKS + PREP_BLOCKS, 256, 0, stream>>>(
        xtr, xt, A, ytr, kq, yfh, numer);
    simmain_kernel<<<dim3(NT / 128, JS), 512, 0, stream>>>(
        kq, yfh, numer, denom);
    finalize_kernel<<<(NT * NCLS) / 256, 256, 0, stream>>>(numer, denom, out);
}